// Round 12
// baseline (182.717 us; speedup 1.0000x reference)
//
#include <hip/hip_runtime.h>
#include <hip/hip_bf16.h>

typedef __bf16 bf16;
typedef __bf16 bf16x8 __attribute__((ext_vector_type(8)));
typedef __bf16 bf16x4 __attribute__((ext_vector_type(4)));
typedef float f32x4 __attribute__((ext_vector_type(4)));
typedef unsigned short ushort4v __attribute__((ext_vector_type(4)));

#define HID 1024
#define SEQL 2048
#define NB 4

#define AS1 __attribute__((address_space(1)))
#define AS3 __attribute__((address_space(3)))

// ---------------- fused fp32 -> bf16 cast (x, W*) + bias concat + RS zero ----------------
__global__ __launch_bounds__(256) void cast_all(const float* __restrict__ x,
    const float* __restrict__ Wq, const float* __restrict__ Wk,
    const float* __restrict__ Wv, const float* __restrict__ Wo,
    const float* __restrict__ bq, const float* __restrict__ bk, const float* __restrict__ bv,
    bf16* __restrict__ XB, bf16* __restrict__ WQKVB, bf16* __restrict__ WOB,
    float* __restrict__ bqkv, float* __restrict__ RS) {
  const int b = blockIdx.x;
  if (b >= 12300) {  // 32 blocks: zero RS[8192] (atomic rowsum target, must be 0 each call)
    RS[(b - 12300) * 256 + threadIdx.x] = 0.0f;
    return;
  }
  if (b >= 12288) {  // 12 blocks: concat q/k/v biases [3072]
    const int i = (b - 12288) * 256 + threadIdx.x;
    bqkv[i] = (i < HID) ? bq[i] : (i < 2 * HID ? bk[i - HID] : bv[i - 2 * HID]);
    return;
  }
  const float* src; bf16* dst; long base;
  if (b < 8192) { src = x; dst = XB; base = (long)b * 256; }
  else {
    const int w = (b - 8192) >> 10, r = (b - 8192) & 1023;
    src = (w == 0) ? Wq : (w == 1) ? Wk : (w == 2) ? Wv : Wo;
    dst = (w == 3) ? WOB : WQKVB + (long)w * (HID * HID);
    base = (long)r * 256;
  }
  const long i = base + threadIdx.x;
  float4 v = reinterpret_cast<const float4*>(src)[i];
  bf16x4 o = { (bf16)v.x, (bf16)v.y, (bf16)v.z, (bf16)v.w };
  reinterpret_cast<bf16x4*>(dst)[i] = o;
}

// ---------------- NT GEMM 256x128, 512 thr (QKV & scores) ----------------
// Single-barrier counted-vmcnt pipeline (R4/R8 structure): 3 round-robin LDS buffers
// (72 KB -> 2 blocks/CU); steady-state wait vmcnt(3); one barrier per K-step; T2 swizzle
// via pre-swizzled global source. EXPP: causal mask + max-free exp -> P', per-row partial
// sums shfl_xor-reduced (16-lane groups) and atomicAdd'ed into rs. QKVSC: 1/32 on q cols.
// SWZ: XCD-chunked block swizzle. CSKIP dead blocks (bj > 2bi+1) do the V->VT 64x64
// transpose instead (grid-stride by dense rank), hiding it under scores compute.
template <typename OutT, bool BIAS, bool CSKIP, bool EXPP, bool QKVSC, bool SWZ>
__global__ __launch_bounds__(512, 4)
void gemm_nt(const bf16* __restrict__ A, const bf16* __restrict__ B,
             const float* __restrict__ bias, OutT* __restrict__ C,
             float* __restrict__ rs, const bf16* __restrict__ vsrc, bf16* __restrict__ vdst,
             int K, int lda, int ldb, int N, long sA, long sB, long sC) {
  int bj, bi;
  if (SWZ) {
    const int lin = blockIdx.x + gridDim.x * blockIdx.y;
    const int chunk = (gridDim.x * gridDim.y) >> 3;
    const int lg = (lin & 7) * chunk + (lin >> 3);
    bj = lg % gridDim.x; bi = lg / gridDim.x;
  } else { bj = blockIdx.x; bi = blockIdx.y; }
  const int bz = blockIdx.z;
  const int t = threadIdx.x;

  __shared__ bf16 lds[3][12288];  // per buf: A 256x32 (8192 el) + B 128x32 (4096 el)

  if (CSKIP && bj > 2 * bi + 1) {
    // fully-masked causal block: do V->VT transpose slices instead (idle-slot reuse).
    bf16 (*tile)[72] = (bf16(*)[72])&lds[0][0];
    const int rank = bz * 56 + (14 * bi - bi * (bi - 1)) + (bj - (2 * bi + 2));  // 0..223
    const int r = t >> 4;          // 0..31
    const int c = (t & 15) * 4;    // 0..60
    for (int w = rank; w < 2048; w += 224) {   // 2048 = NB*(SEQL/64)*(HID/64)
      const int b = w >> 9;
      const int wi = w & 511;
      const int s0 = (wi & 31) * 64;
      const int h0 = (wi >> 5) * 64;
      const bf16* src = vsrc + ((long)b * SEQL + s0) * (3 * HID) + h0;
#pragma unroll
      for (int rr = 0; rr < 2; ++rr) {
        const int row = r + rr * 32;
        *reinterpret_cast<ushort4v*>(&tile[row][c]) =
            *reinterpret_cast<const ushort4v*>(src + (long)row * (3 * HID) + c);
      }
      __syncthreads();
      bf16* dst = vdst + ((long)b * HID + h0) * SEQL + s0;
#pragma unroll
      for (int rr = 0; rr < 2; ++rr) {
        const int hr = r + rr * 32;
        bf16x4 o = { tile[c + 0][hr], tile[c + 1][hr], tile[c + 2][hr], tile[c + 3][hr] };
        *reinterpret_cast<bf16x4*>(dst + (long)hr * SEQL + c) = o;
      }
      __syncthreads();
    }
    return;
  }

  A += (long)bz * sA + (long)bi * 256 * lda;
  B += (long)bz * sB + (long)bj * 128 * ldb;
  const int nt = K >> 5;

  const int lane = t & 63;
  const int wid = t >> 6;
  const int wr = (wid >> 1) * 64;   // wave row offset
  const int wc = (wid & 1) * 64;    // wave col offset
  const int frow = lane & 15;
  const int l = lane >> 4;  // k-granule 0..3

  const int sr = t >> 2;                               // staging row 0..127
  const int scol = (((t & 3) ^ ((t >> 3) & 3)) << 3);  // inverse-swizzled src col

  int offA[4], offB[4];
#pragma unroll
  for (int m = 0; m < 4; ++m) {
    const int r = wr + m * 16 + frow;
    offA[m] = r * 32 + ((l ^ ((r >> 1) & 3)) << 3);
  }
#pragma unroll
  for (int n = 0; n < 4; ++n) {
    const int r = wc + n * 16 + frow;
    offB[n] = 8192 + r * 32 + ((l ^ ((r >> 1) & 3)) << 3);
  }

  f32x4 acc[4][4] = {};

#define STAGE(bufi, tile_)                                                               \
  {                                                                                      \
    const int kk = (tile_) << 5;                                                         \
    bf16* lb = &lds[bufi][0];                                                            \
    __builtin_amdgcn_global_load_lds(                                                    \
        (const AS1 void*)(A + (long)sr * lda + kk + scol),                               \
        (AS3 void*)(lb + t * 8), 16, 0, 0);                                              \
    __builtin_amdgcn_global_load_lds(                                                    \
        (const AS1 void*)(A + (long)(sr + 128) * lda + kk + scol),                       \
        (AS3 void*)(lb + 4096 + t * 8), 16, 0, 0);                                       \
    __builtin_amdgcn_global_load_lds(                                                    \
        (const AS1 void*)(B + (long)sr * ldb + kk + scol),                               \
        (AS3 void*)(lb + 8192 + t * 8), 16, 0, 0);                                       \
  }

  STAGE(0, 0);
  STAGE(1, 1);                                      // 6 loads in flight
  asm volatile("s_waitcnt vmcnt(3)" ::: "memory");  // tile 0 landed
  __builtin_amdgcn_s_barrier();
  __builtin_amdgcn_sched_barrier(0);

  int rb = 0;  // buffer holding tile tt
  for (int tt = 0; tt < nt; ++tt) {
    const bf16* lb = &lds[rb][0];
    bf16x8 af[4], bfr[4];
#pragma unroll
    for (int m = 0; m < 4; ++m) af[m] = *reinterpret_cast<const bf16x8*>(lb + offA[m]);
#pragma unroll
    for (int n = 0; n < 4; ++n) bfr[n] = *reinterpret_cast<const bf16x8*>(lb + offB[n]);
    int sb = rb + 2; if (sb >= 3) sb -= 3;
    if (tt + 2 < nt) STAGE(sb, tt + 2);  // writes buf[(tt-1)%3]: reads of it done pre-barrier
    __builtin_amdgcn_s_setprio(1);
#pragma unroll
    for (int m = 0; m < 4; ++m)
#pragma unroll
      for (int n = 0; n < 4; ++n)
        acc[m][n] = __builtin_amdgcn_mfma_f32_16x16x32_bf16(af[m], bfr[n], acc[m][n], 0, 0, 0);
    __builtin_amdgcn_s_setprio(0);
    __builtin_amdgcn_sched_barrier(0);
    if (tt + 2 < nt)      { asm volatile("s_waitcnt vmcnt(3)" ::: "memory"); }
    else if (tt + 1 < nt) { asm volatile("s_waitcnt vmcnt(0)" ::: "memory"); }
    if (tt + 1 < nt) {
      __builtin_amdgcn_s_barrier();
      __builtin_amdgcn_sched_barrier(0);
    }
    rb = (rb + 1 == 3) ? 0 : rb + 1;
  }
#undef STAGE

  // epilogue: C/D frag layout col=lane&15, row=(lane>>4)*4+rr
  const int crow = l * 4;
  const int ccol = frow;
#pragma unroll
  for (int m = 0; m < 4; ++m) {
#pragma unroll
    for (int rr = 0; rr < 4; ++rr) {
      const int rowl = wr + m * 16 + crow + rr;
      const long row = (long)bi * 256 + rowl;
      float part = 0.0f;
#pragma unroll
      for (int n = 0; n < 4; ++n) {
        const int coll = wc + n * 16 + ccol;
        const int colg = bj * 128 + coll;
        float v = acc[m][n][rr];
        if (EXPP) { v = (colg <= row) ? __expf(v) : 0.0f; part += v; }
        else {
          const float bv = BIAS ? bias[colg] : 0.0f;
          const float sc = QKVSC ? (colg < HID ? 0.03125f : 1.0f) : 1.0f;
          v = (v + bv) * sc;
        }
        C[(long)bz * sC + row * N + colg] = (OutT)v;
      }
      if (EXPP) {
        part += __shfl_xor(part, 1);
        part += __shfl_xor(part, 2);
        part += __shfl_xor(part, 4);
        part += __shfl_xor(part, 8);
        if (frow == 0) atomicAdd(&rs[(long)bz * SEQL + row], part);
      }
    }
  }
}

// ---------------- NT GEMM 128x128, 256 thr, 3 blocks/CU (PV & outproj) ----------------
// Same per-wave schedule (3-buf round-robin, counted vmcnt(4), one barrier/K-step, T2
// swizzle); smaller block composition -> bigger grids, better fill for small GEMMs.
// KLIM: causal K-limit (bi+1)*128. RSDIV: multiply by 1/rs[bz*SEQL+row].
template <typename OutT, bool BIAS, bool KLIM, bool RSDIV, bool SWZ>
__global__ __launch_bounds__(256, 3)
void gemm128(const bf16* __restrict__ A, const bf16* __restrict__ B,
             const float* __restrict__ bias, OutT* __restrict__ C,
             const float* __restrict__ rs,
             int K, int lda, int ldb, int N, long sA, long sB, long sC) {
  int bj, bi;
  if (SWZ) {
    const int lin = blockIdx.x + gridDim.x * blockIdx.y;
    const int chunk = (gridDim.x * gridDim.y) >> 3;
    const int lg = (lin & 7) * chunk + (lin >> 3);
    bj = lg % gridDim.x; bi = lg / gridDim.x;
  } else { bj = blockIdx.x; bi = blockIdx.y; }
  const int bz = blockIdx.z;
  A += (long)bz * sA + (long)bi * 128 * lda;
  B += (long)bz * sB + (long)bj * 128 * ldb;
  const int Kend = KLIM ? ((bi + 1) * 128) : K;
  const int nt = Kend >> 5;  // >= 4

  __shared__ bf16 lds[3][8192];  // per buf: A 128x32 + B 128x32

  const int t = threadIdx.x;
  const int lane = t & 63;
  const int wid = t >> 6;
  const int wr = (wid >> 1) * 64;
  const int wc = (wid & 1) * 64;
  const int frow = lane & 15;
  const int l = lane >> 4;

  const int sr = t >> 2;                               // staging row 0..63
  const int scol = (((t & 3) ^ ((t >> 3) & 3)) << 3);  // inverse-swizzled src col

  int offA[4], offB[4];
#pragma unroll
  for (int m = 0; m < 4; ++m) {
    const int r = wr + m * 16 + frow;
    offA[m] = r * 32 + ((l ^ ((r >> 1) & 3)) << 3);
  }
#pragma unroll
  for (int n = 0; n < 4; ++n) {
    const int r = wc + n * 16 + frow;
    offB[n] = 4096 + r * 32 + ((l ^ ((r >> 1) & 3)) << 3);
  }

  f32x4 acc[4][4] = {};

#define STAGE(bufi, tile_)                                                                \
  {                                                                                       \
    const int kk = (tile_) << 5;                                                          \
    bf16* lb = &lds[bufi][0];                                                             \
    _Pragma("unroll") for (int j = 0; j < 2; ++j)                                         \
      __builtin_amdgcn_global_load_lds(                                                   \
          (const AS1 void*)(A + (long)(sr + j * 64) * lda + kk + scol),                   \
          (AS3 void*)(lb + j * 2048 + t * 8), 16, 0, 0);                                  \
    _Pragma("unroll") for (int j = 0; j < 2; ++j)                                         \
      __builtin_amdgcn_global_load_lds(                                                   \
          (const AS1 void*)(B + (long)(sr + j * 64) * ldb + kk + scol),                   \
          (AS3 void*)(lb + 4096 + j * 2048 + t * 8), 16, 0, 0);                           \
  }

  STAGE(0, 0);
  STAGE(1, 1);                                      // 8 loads in flight
  asm volatile("s_waitcnt vmcnt(4)" ::: "memory");  // tile 0 landed
  __builtin_amdgcn_s_barrier();
  __builtin_amdgcn_sched_barrier(0);

  int rb = 0;
  for (int tt = 0; tt < nt; ++tt) {
    const bf16* lb = &lds[rb][0];
    bf16x8 af[4], bfr[4];
#pragma unroll
    for (int m = 0; m < 4; ++m) af[m] = *reinterpret_cast<const bf16x8*>(lb + offA[m]);
#pragma unroll
    for (int n = 0; n < 4; ++n) bfr[n] = *reinterpret_cast<const bf16x8*>(lb + offB[n]);
    int sb = rb + 2; if (sb >= 3) sb -= 3;
    if (tt + 2 < nt) STAGE(sb, tt + 2);
    __builtin_amdgcn_s_setprio(1);
#pragma unroll
    for (int m = 0; m < 4; ++m)
#pragma unroll
      for (int n = 0; n < 4; ++n)
        acc[m][n] = __builtin_amdgcn_mfma_f32_16x16x32_bf16(af[m], bfr[n], acc[m][n], 0, 0, 0);
    __builtin_amdgcn_s_setprio(0);
    __builtin_amdgcn_sched_barrier(0);
    if (tt + 2 < nt)      { asm volatile("s_waitcnt vmcnt(4)" ::: "memory"); }
    else if (tt + 1 < nt) { asm volatile("s_waitcnt vmcnt(0)" ::: "memory"); }
    if (tt + 1 < nt) {
      __builtin_amdgcn_s_barrier();
      __builtin_amdgcn_sched_barrier(0);
    }
    rb = (rb + 1 == 3) ? 0 : rb + 1;
  }
#undef STAGE

  const int crow = l * 4;
  const int ccol = frow;
#pragma unroll
  for (int m = 0; m < 4; ++m) {
#pragma unroll
    for (int rr = 0; rr < 4; ++rr) {
      const int rowl = wr + m * 16 + crow + rr;
      const long row = (long)bi * 128 + rowl;
      const float rsv = RSDIV ? (1.0f / rs[(long)bz * SEQL + row]) : 1.0f;
#pragma unroll
      for (int n = 0; n < 4; ++n) {
        const int coll = wc + n * 16 + ccol;
        const int colg = bj * 128 + coll;
        float v = acc[m][n][rr];
        if (BIAS) v += bias[colg];
        if (RSDIV) v *= rsv;
        C[(long)bz * sC + row * N + colg] = (OutT)v;
      }
    }
  }
}

extern "C" void kernel_launch(void* const* d_in, const int* in_sizes, int n_in,
                              void* d_out, int out_size, void* d_ws, size_t ws_size,
                              hipStream_t stream) {
  const float* x  = (const float*)d_in[0];
  const float* Wq = (const float*)d_in[1];
  const float* bq = (const float*)d_in[2];
  const float* Wk = (const float*)d_in[3];
  const float* bk = (const float*)d_in[4];
  const float* Wv = (const float*)d_in[5];
  const float* bv = (const float*)d_in[6];
  const float* Wo = (const float*)d_in[7];
  const float* bo = (const float*)d_in[8];
  float* out = (float*)d_out;

  // workspace (~136.4 MiB), lifetime-safe aliasing (as R8/R11):
  char* ws = (char*)d_ws;
  bf16*  XB    = (bf16*)(ws);
  bf16*  WQKVB = (bf16*)(ws + 16777216L);
  float* bqkv  = (float*)(ws + 23068672L);
  bf16*  QKV   = (bf16*)(ws + 33554432L);
  bf16*  CTX   = (bf16*)(ws + 33554432L);
  bf16*  VT    = (bf16*)(ws + 83886080L);
  bf16*  WOB   = (bf16*)(ws + 100663296L);
  bf16*  P     = (bf16*)(ws + 102760448L);
  float* RS    = (float*)(ws + 136314880L);

  // 1) fused casts + bias concat + RS zero
  cast_all<<<12332, 256, 0, stream>>>(x, Wq, Wk, Wv, Wo, bq, bk, bv, XB, WQKVB, WOB, bqkv, RS);

  // 2) QKV projection: [8192,1024] x [3072,1024]^T; q-cols scaled 1/32 (XCD-swizzled)
  gemm_nt<bf16, true, false, false, true, true><<<dim3(24, 32, 1), 512, 0, stream>>>(
      XB, WQKVB, bqkv, QKV, nullptr, nullptr, nullptr, HID, HID, HID, 3 * HID, 0, 0, 0);

  // 3) P' = exp(q.k^T) causal, bf16, + atomic row sums; dead causal blocks do V->VT transpose
  gemm_nt<bf16, false, true, true, false, false><<<dim3(16, 8, NB), 512, 0, stream>>>(
      QKV, QKV + HID, nullptr, P, RS, QKV + 2 * HID, VT, HID, 3 * HID, 3 * HID, SEQL,
      (long)SEQL * 3 * HID, (long)SEQL * 3 * HID, (long)SEQL * SEQL);

  // 4) ctx = (P' @ v) / rowsum (causal K-limit, 128-granular; 3 blk/CU fill)
  gemm128<bf16, false, true, true, false><<<dim3(8, 16, NB), 256, 0, stream>>>(
      P, VT, nullptr, CTX, RS, SEQL, SEQL, SEQL, HID,
      (long)SEQL * SEQL, (long)HID * SEQL, (long)SEQL * HID);

  // 5) out = ctx @ Wo^T + bo (XCD-swizzled; 3 blk/CU fill)
  gemm128<float, true, false, false, true><<<dim3(8, 64, 1), 256, 0, stream>>>(
      CTX, WOB, bo, out, nullptr, HID, HID, HID, HID, 0, 0, 0);
}

// Round 13
// 169.124 us; speedup vs baseline: 1.0804x; 1.0804x over previous
//
#include <hip/hip_runtime.h>
#include <hip/hip_bf16.h>

typedef __bf16 bf16;
typedef __bf16 bf16x8 __attribute__((ext_vector_type(8)));
typedef __bf16 bf16x4 __attribute__((ext_vector_type(4)));
typedef float f32x4 __attribute__((ext_vector_type(4)));

#define HID 1024
#define SEQL 2048
#define NB 4

#define AS1 __attribute__((address_space(1)))
#define AS3 __attribute__((address_space(3)))

// ---------------- fused fp32 -> bf16 cast (x, W*) + bias concat + RS zero ----------------
__global__ __launch_bounds__(256) void cast_all(const float* __restrict__ x,
    const float* __restrict__ Wq, const float* __restrict__ Wk,
    const float* __restrict__ Wv, const float* __restrict__ Wo,
    const float* __restrict__ bq, const float* __restrict__ bk, const float* __restrict__ bv,
    bf16* __restrict__ XB, bf16* __restrict__ WQKVB, bf16* __restrict__ WOB,
    float* __restrict__ bqkv, float* __restrict__ RS) {
  const int b = blockIdx.x;
  if (b >= 12300) {  // 32 blocks: zero RS[8192] (atomic rowsum target, must be 0 each call)
    RS[(b - 12300) * 256 + threadIdx.x] = 0.0f;
    return;
  }
  if (b >= 12288) {  // 12 blocks: concat q/k/v biases [3072]
    const int i = (b - 12288) * 256 + threadIdx.x;
    bqkv[i] = (i < HID) ? bq[i] : (i < 2 * HID ? bk[i - HID] : bv[i - 2 * HID]);
    return;
  }
  const float* src; bf16* dst; long base;
  if (b < 8192) { src = x; dst = XB; base = (long)b * 256; }
  else {
    const int w = (b - 8192) >> 10, r = (b - 8192) & 1023;
    src = (w == 0) ? Wq : (w == 1) ? Wk : (w == 2) ? Wv : Wo;
    dst = (w == 3) ? WOB : WQKVB + (long)w * (HID * HID);
    base = (long)r * 256;
  }
  const long i = base + threadIdx.x;
  float4 v = reinterpret_cast<const float4*>(src)[i];
  bf16x4 o = { (bf16)v.x, (bf16)v.y, (bf16)v.z, (bf16)v.w };
  reinterpret_cast<bf16x4*>(dst)[i] = o;
}

// ======== shared pipeline pieces (256x128 tile, BK=32, 512 thr, 3-buf counted vmcnt) ========
#define PIPE_DECLS                                                                        \
  const int lane = t & 63;                                                                \
  const int wid = t >> 6;                                                                 \
  const int wr = (wid >> 1) * 64;                                                         \
  const int wc = (wid & 1) * 64;                                                          \
  const int frow = lane & 15;                                                             \
  const int l = lane >> 4;                                                                \
  const int sr = t >> 2;                                                                  \
  const int scol = (((t & 3) ^ ((t >> 3) & 3)) << 3);                                     \
  int offA[4], offB[4];                                                                   \
  _Pragma("unroll") for (int m = 0; m < 4; ++m) {                                         \
    const int r = wr + m * 16 + frow;                                                     \
    offA[m] = r * 32 + ((l ^ ((r >> 1) & 3)) << 3);                                       \
  }                                                                                       \
  _Pragma("unroll") for (int n = 0; n < 4; ++n) {                                         \
    const int r = wc + n * 16 + frow;                                                     \
    offB[n] = 8192 + r * 32 + ((l ^ ((r >> 1) & 3)) << 3);                                \
  }                                                                                       \
  f32x4 acc[4][4] = {};

#define STAGE(bufi, tile_)                                                                \
  {                                                                                       \
    const int kk = (tile_) << 5;                                                          \
    bf16* lb = &lds[bufi][0];                                                             \
    __builtin_amdgcn_global_load_lds(                                                     \
        (const AS1 void*)(Ab + (long)sr * lda + kk + scol),                               \
        (AS3 void*)(lb + t * 8), 16, 0, 0);                                               \
    __builtin_amdgcn_global_load_lds(                                                     \
        (const AS1 void*)(Ab + (long)(sr + 128) * lda + kk + scol),                       \
        (AS3 void*)(lb + 4096 + t * 8), 16, 0, 0);                                        \
    __builtin_amdgcn_global_load_lds(                                                     \
        (const AS1 void*)(Bb + (long)sr * ldb + kk + scol),                               \
        (AS3 void*)(lb + 8192 + t * 8), 16, 0, 0);                                        \
  }

#define PIPE_LOOP                                                                         \
  STAGE(0, 0);                                                                            \
  STAGE(1, 1);                                                                            \
  asm volatile("s_waitcnt vmcnt(3)" ::: "memory");                                        \
  __builtin_amdgcn_s_barrier();                                                           \
  __builtin_amdgcn_sched_barrier(0);                                                      \
  int rb = 0;                                                                             \
  for (int tt = 0; tt < nt; ++tt) {                                                       \
    const bf16* lb = &lds[rb][0];                                                         \
    bf16x8 af[4], bfr[4];                                                                 \
    _Pragma("unroll") for (int m = 0; m < 4; ++m)                                         \
        af[m] = *reinterpret_cast<const bf16x8*>(lb + offA[m]);                           \
    _Pragma("unroll") for (int n = 0; n < 4; ++n)                                         \
        bfr[n] = *reinterpret_cast<const bf16x8*>(lb + offB[n]);                          \
    int sb = rb + 2; if (sb >= 3) sb -= 3;                                                \
    if (tt + 2 < nt) STAGE(sb, tt + 2);                                                   \
    __builtin_amdgcn_s_setprio(1);                                                        \
    _Pragma("unroll") for (int m = 0; m < 4; ++m)                                         \
      _Pragma("unroll") for (int n = 0; n < 4; ++n)                                       \
          acc[m][n] = __builtin_amdgcn_mfma_f32_16x16x32_bf16(af[m], bfr[n], acc[m][n], 0, 0, 0); \
    __builtin_amdgcn_s_setprio(0);                                                        \
    __builtin_amdgcn_sched_barrier(0);                                                    \
    if (tt + 2 < nt)      { asm volatile("s_waitcnt vmcnt(3)" ::: "memory"); }            \
    else if (tt + 1 < nt) { asm volatile("s_waitcnt vmcnt(0)" ::: "memory"); }            \
    if (tt + 1 < nt) {                                                                    \
      __builtin_amdgcn_s_barrier();                                                       \
      __builtin_amdgcn_sched_barrier(0);                                                  \
    }                                                                                     \
    rb = (rb + 1 == 3) ? 0 : rb + 1;                                                      \
  }

// ---------------- NT GEMM 256x128 (QKV projection & final P'W2^T) ----------------
// KLIM: causal K-limit (bi+1)*256. RSDIV: v *= 1/rs[bz*SEQL+row] (before bias).
// QKVSC: 1/32 on q columns (after bias). SWZ: XCD-chunked blockIdx swizzle.
template <typename OutT, bool BIAS, bool KLIM, bool RSDIV, bool QKVSC, bool SWZ>
__global__ __launch_bounds__(512, 4)
void gemm_nt(const bf16* __restrict__ A, const bf16* __restrict__ B,
             const float* __restrict__ bias, OutT* __restrict__ C,
             const float* __restrict__ rs,
             int K, int lda, int ldb, int N, long sA, long sB, long sC) {
  int bj, bi;
  if (SWZ) {
    const int lin = blockIdx.x + gridDim.x * blockIdx.y;
    const int chunk = (gridDim.x * gridDim.y) >> 3;
    const int lg = (lin & 7) * chunk + (lin >> 3);
    bj = lg % gridDim.x; bi = lg / gridDim.x;
  } else { bj = blockIdx.x; bi = blockIdx.y; }
  const int bz = blockIdx.z;
  const int t = threadIdx.x;
  const bf16* Ab = A + (long)bz * sA + (long)bi * 256 * lda;
  const bf16* Bb = B + (long)bz * sB + (long)bj * 128 * ldb;
  const int Kend = KLIM ? ((bi + 1) * 256) : K;
  const int nt = Kend >> 5;

  __shared__ bf16 lds[3][12288];
  PIPE_DECLS
  PIPE_LOOP

  const int crow = l * 4;
  const int ccol = frow;
#pragma unroll
  for (int m = 0; m < 4; ++m) {
#pragma unroll
    for (int rr = 0; rr < 4; ++rr) {
      const int rowl = wr + m * 16 + crow + rr;
      const long row = (long)bi * 256 + rowl;
      const float rsv = RSDIV ? (1.0f / rs[(long)bz * SEQL + row]) : 1.0f;
#pragma unroll
      for (int n = 0; n < 4; ++n) {
        const int coll = wc + n * 16 + ccol;
        const int colg = bj * 128 + coll;
        float v = acc[m][n][rr];
        if (RSDIV) v *= rsv;
        if (BIAS)  v += bias[colg];
        if (QKVSC) v *= (colg < HID ? 0.03125f : 1.0f);
        C[(long)bz * sC + row * N + colg] = (OutT)v;
      }
    }
  }
}

// ---------------- scores + W2, one dispatch, grid (17,8,4) ----------------
// Live blocks (bj <= 2bi+1): P' tile = exp(q.k^T) causal (max-free), bf16, + atomic
// row sums into rs. Dead blocks (256 of them = exactly W2's tiles): W2 = Wo @ V^T,
// i.e. NT GEMM A=Wo[1024,1024], B=V (ldb 3072), C=W2[wz][1024][2048] — replaces both
// the V->VT transpose and the output projection (out = (P' W2^T)/rs + bo).
__global__ __launch_bounds__(512, 4)
void scores_w2(const bf16* __restrict__ Q, const bf16* __restrict__ Kp,
               const bf16* __restrict__ Wo, const bf16* __restrict__ V,
               bf16* __restrict__ P, bf16* __restrict__ W2, float* __restrict__ rs) {
  const int bj = blockIdx.x, bi = blockIdx.y, bz = blockIdx.z;  // (17,8,4)
  const int t = threadIdx.x;
  const bool live = (bj <= 2 * bi + 1);
  const bf16 *Ab, *Bb;
  bf16* Cb;
  int lda, ldb;
  if (live) {
    Ab = Q + ((long)bz * SEQL + (long)bi * 256) * (3 * HID);
    Bb = Kp + ((long)bz * SEQL + (long)bj * 128) * (3 * HID);
    Cb = P + ((long)bz * SEQL + (long)bi * 256) * SEQL + bj * 128;
    lda = 3 * HID; ldb = 3 * HID;
  } else {
    // dense rank over dead slots: per-bi dead = 15-2bi, prefix = 15bi - bi(bi-1)
    const int rank = bz * 64 + (15 * bi - bi * (bi - 1)) + (bj - (2 * bi + 2));  // 0..255
    const int wz = rank >> 6, r = rank & 63, mi = r >> 4, nj = r & 15;
    Ab = Wo + (long)mi * 256 * HID;
    Bb = V + ((long)wz * SEQL + (long)nj * 128) * (3 * HID);
    Cb = W2 + ((long)wz * HID + (long)mi * 256) * SEQL + nj * 128;
    lda = HID; ldb = 3 * HID;
  }
  const int nt = 32;  // K = 1024

  __shared__ bf16 lds[3][12288];
  PIPE_DECLS
  PIPE_LOOP

  const int crow = l * 4;
  const int ccol = frow;
#pragma unroll
  for (int m = 0; m < 4; ++m) {
#pragma unroll
    for (int rr = 0; rr < 4; ++rr) {
      const int rowl = wr + m * 16 + crow + rr;
      float part = 0.0f;
#pragma unroll
      for (int n = 0; n < 4; ++n) {
        const int coll = wc + n * 16 + ccol;
        float v = acc[m][n][rr];
        if (live) {
          const int row = bi * 256 + rowl;
          const int col = bj * 128 + coll;
          v = (col <= row) ? __expf(v) : 0.0f;  // causal mask + max-free exp
          part += v;
        }
        Cb[(long)rowl * SEQL + coll] = (bf16)v;
      }
      if (live) {
        part += __shfl_xor(part, 1);
        part += __shfl_xor(part, 2);
        part += __shfl_xor(part, 4);
        part += __shfl_xor(part, 8);
        if (frow == 0) atomicAdd(&rs[(long)bz * SEQL + bi * 256 + rowl], part);
      }
    }
  }
}

extern "C" void kernel_launch(void* const* d_in, const int* in_sizes, int n_in,
                              void* d_out, int out_size, void* d_ws, size_t ws_size,
                              hipStream_t stream) {
  const float* x  = (const float*)d_in[0];
  const float* Wq = (const float*)d_in[1];
  const float* bq = (const float*)d_in[2];
  const float* Wk = (const float*)d_in[3];
  const float* bk = (const float*)d_in[4];
  const float* Wv = (const float*)d_in[5];
  const float* bv = (const float*)d_in[6];
  const float* Wo = (const float*)d_in[7];
  const float* bo = (const float*)d_in[8];
  float* out = (float*)d_out;

  // workspace (~136.4 MiB), lifetime-safe aliasing:
  //  [0      ,16.78M)  XB
  //  [16.78M ,23.07M)  WQKVB ; [23.07M,+12KB) bqkv
  //  [33.55M ,83.89M)  QKV bf16 [8192][3072]
  //  [83.89M ,100.66M) W2 bf16 [4][1024][2048]  (was VT)
  //  [100.66M,102.76M) WOB
  //  [102.76M,136.31M) P' bf16 [8192][2048]
  //  [136.31M,+32KB)   RS (atomic rowsums, f32)
  char* ws = (char*)d_ws;
  bf16*  XB    = (bf16*)(ws);
  bf16*  WQKVB = (bf16*)(ws + 16777216L);
  float* bqkv  = (float*)(ws + 23068672L);
  bf16*  QKV   = (bf16*)(ws + 33554432L);
  bf16*  W2    = (bf16*)(ws + 83886080L);
  bf16*  WOB   = (bf16*)(ws + 100663296L);
  bf16*  P     = (bf16*)(ws + 102760448L);
  float* RS    = (float*)(ws + 136314880L);

  // 1) fused casts + bias concat + RS zero
  cast_all<<<12332, 256, 0, stream>>>(x, Wq, Wk, Wv, Wo, bq, bk, bv, XB, WQKVB, WOB, bqkv, RS);

  // 2) QKV projection: [8192,1024] x [3072,1024]^T; q-cols scaled 1/32 (XCD-swizzled)
  gemm_nt<bf16, true, false, false, true, true><<<dim3(24, 32, 1), 512, 0, stream>>>(
      XB, WQKVB, bqkv, QKV, nullptr, HID, HID, HID, 3 * HID, 0, 0, 0);

  // 3) P' = exp(q.k^T) causal + atomic row sums; dead causal slots compute W2 = Wo V^T
  scores_w2<<<dim3(17, 8, NB), 512, 0, stream>>>(
      QKV, QKV + HID, WOB, QKV + 2 * HID, P, W2, RS);

  // 4) out = (P' @ W2^T) / rowsum + bo   (causal K-limit, 256-granular)
  gemm_nt<float, true, true, true, false, false><<<dim3(8, 8, NB), 512, 0, stream>>>(
      P, W2, bo, out, RS, SEQL, SEQL, SEQL, HID,
      (long)SEQL * SEQL, (long)HID * SEQL, (long)SEQL * HID);
}

// Round 14
// 164.349 us; speedup vs baseline: 1.1118x; 1.0290x over previous
//
#include <hip/hip_runtime.h>
#include <hip/hip_bf16.h>

typedef __bf16 bf16;
typedef __bf16 bf16x8 __attribute__((ext_vector_type(8)));
typedef __bf16 bf16x4 __attribute__((ext_vector_type(4)));
typedef float f32x4 __attribute__((ext_vector_type(4)));

#define HID 1024
#define SEQL 2048
#define NB 4

#define AS1 __attribute__((address_space(1)))
#define AS3 __attribute__((address_space(3)))

// ---------------- fused fp32 -> bf16 cast (x, W*) + bias concat + RS zero ----------------
__global__ __launch_bounds__(256) void cast_all(const float* __restrict__ x,
    const float* __restrict__ Wq, const float* __restrict__ Wk,
    const float* __restrict__ Wv, const float* __restrict__ Wo,
    const float* __restrict__ bq, const float* __restrict__ bk, const float* __restrict__ bv,
    bf16* __restrict__ XB, bf16* __restrict__ WQKVB, bf16* __restrict__ WOB,
    float* __restrict__ bqkv, float* __restrict__ RS) {
  const int b = blockIdx.x;
  if (b >= 12300) {  // 32 blocks: zero RS[8192] (atomic rowsum target, must be 0 each call)
    RS[(b - 12300) * 256 + threadIdx.x] = 0.0f;
    return;
  }
  if (b >= 12288) {  // 12 blocks: concat q/k/v biases [3072]
    const int i = (b - 12288) * 256 + threadIdx.x;
    bqkv[i] = (i < HID) ? bq[i] : (i < 2 * HID ? bk[i - HID] : bv[i - 2 * HID]);
    return;
  }
  const float* src; bf16* dst; long base;
  if (b < 8192) { src = x; dst = XB; base = (long)b * 256; }
  else {
    const int w = (b - 8192) >> 10, r = (b - 8192) & 1023;
    src = (w == 0) ? Wq : (w == 1) ? Wk : (w == 2) ? Wv : Wo;
    dst = (w == 3) ? WOB : WQKVB + (long)w * (HID * HID);
    base = (long)r * 256;
  }
  const long i = base + threadIdx.x;
  float4 v = reinterpret_cast<const float4*>(src)[i];
  bf16x4 o = { (bf16)v.x, (bf16)v.y, (bf16)v.z, (bf16)v.w };
  reinterpret_cast<bf16x4*>(dst)[i] = o;
}

// ======== shared pipeline pieces (256x128 tile, BK=32, 512 thr, 3-buf counted vmcnt) ========
#define PIPE_DECLS                                                                        \
  const int lane = t & 63;                                                                \
  const int wid = t >> 6;                                                                 \
  const int wr = (wid >> 1) * 64;                                                         \
  const int wc = (wid & 1) * 64;                                                          \
  const int frow = lane & 15;                                                             \
  const int l = lane >> 4;                                                                \
  const int sr = t >> 2;                                                                  \
  const int scol = (((t & 3) ^ ((t >> 3) & 3)) << 3);                                     \
  int offA[4], offB[4];                                                                   \
  _Pragma("unroll") for (int m = 0; m < 4; ++m) {                                         \
    const int r = wr + m * 16 + frow;                                                     \
    offA[m] = r * 32 + ((l ^ ((r >> 1) & 3)) << 3);                                       \
  }                                                                                       \
  _Pragma("unroll") for (int n = 0; n < 4; ++n) {                                         \
    const int r = wc + n * 16 + frow;                                                     \
    offB[n] = 8192 + r * 32 + ((l ^ ((r >> 1) & 3)) << 3);                                \
  }                                                                                       \
  f32x4 acc[4][4] = {};

#define STAGE(bufi, tile_)                                                                \
  {                                                                                       \
    const int kk = (tile_) << 5;                                                          \
    bf16* lb = &lds[bufi][0];                                                             \
    __builtin_amdgcn_global_load_lds(                                                     \
        (const AS1 void*)(Ab + (long)sr * lda + kk + scol),                               \
        (AS3 void*)(lb + t * 8), 16, 0, 0);                                               \
    __builtin_amdgcn_global_load_lds(                                                     \
        (const AS1 void*)(Ab + (long)(sr + 128) * lda + kk + scol),                       \
        (AS3 void*)(lb + 4096 + t * 8), 16, 0, 0);                                        \
    __builtin_amdgcn_global_load_lds(                                                     \
        (const AS1 void*)(Bb + (long)sr * ldb + kk + scol),                               \
        (AS3 void*)(lb + 8192 + t * 8), 16, 0, 0);                                        \
  }

#define PIPE_LOOP                                                                         \
  STAGE(0, 0);                                                                            \
  STAGE(1, 1);                                                                            \
  asm volatile("s_waitcnt vmcnt(3)" ::: "memory");                                        \
  __builtin_amdgcn_s_barrier();                                                           \
  __builtin_amdgcn_sched_barrier(0);                                                      \
  int rb = 0;                                                                             \
  for (int tt = 0; tt < nt; ++tt) {                                                       \
    const bf16* lb = &lds[rb][0];                                                         \
    bf16x8 af[4], bfr[4];                                                                 \
    _Pragma("unroll") for (int m = 0; m < 4; ++m)                                         \
        af[m] = *reinterpret_cast<const bf16x8*>(lb + offA[m]);                           \
    _Pragma("unroll") for (int n = 0; n < 4; ++n)                                         \
        bfr[n] = *reinterpret_cast<const bf16x8*>(lb + offB[n]);                          \
    int sb = rb + 2; if (sb >= 3) sb -= 3;                                                \
    if (tt + 2 < nt) STAGE(sb, tt + 2);                                                   \
    __builtin_amdgcn_s_setprio(1);                                                        \
    _Pragma("unroll") for (int m = 0; m < 4; ++m)                                         \
      _Pragma("unroll") for (int n = 0; n < 4; ++n)                                       \
          acc[m][n] = __builtin_amdgcn_mfma_f32_16x16x32_bf16(af[m], bfr[n], acc[m][n], 0, 0, 0); \
    __builtin_amdgcn_s_setprio(0);                                                        \
    __builtin_amdgcn_sched_barrier(0);                                                    \
    if (tt + 2 < nt)      { asm volatile("s_waitcnt vmcnt(3)" ::: "memory"); }            \
    else if (tt + 1 < nt) { asm volatile("s_waitcnt vmcnt(0)" ::: "memory"); }            \
    if (tt + 1 < nt) {                                                                    \
      __builtin_amdgcn_s_barrier();                                                       \
      __builtin_amdgcn_sched_barrier(0);                                                  \
    }                                                                                     \
    rb = (rb + 1 == 3) ? 0 : rb + 1;                                                      \
  }

// ---------------- NT GEMM 256x128 (QKV projection & final P'W2^T) ----------------
// KLIM: causal K-limit (bi+1)*256. RSDIV: v *= 1/rs[bz*SEQL+row] (before bias).
// QKVSC: 1/32 on q columns (after bias). SWZ: XCD-chunked blockIdx swizzle.
template <typename OutT, bool BIAS, bool KLIM, bool RSDIV, bool QKVSC, bool SWZ>
__global__ __launch_bounds__(512, 4)
void gemm_nt(const bf16* __restrict__ A, const bf16* __restrict__ B,
             const float* __restrict__ bias, OutT* __restrict__ C,
             const float* __restrict__ rs,
             int K, int lda, int ldb, int N, long sA, long sB, long sC) {
  int bj, bi;
  if (SWZ) {
    const int lin = blockIdx.x + gridDim.x * blockIdx.y;
    const int chunk = (gridDim.x * gridDim.y) >> 3;
    const int lg = (lin & 7) * chunk + (lin >> 3);
    bj = lg % gridDim.x; bi = lg / gridDim.x;
  } else { bj = blockIdx.x; bi = blockIdx.y; }
  const int bz = blockIdx.z;
  const int t = threadIdx.x;
  const bf16* Ab = A + (long)bz * sA + (long)bi * 256 * lda;
  const bf16* Bb = B + (long)bz * sB + (long)bj * 128 * ldb;
  const int Kend = KLIM ? ((bi + 1) * 256) : K;
  const int nt = Kend >> 5;

  __shared__ bf16 lds[3][12288];
  PIPE_DECLS
  PIPE_LOOP

  const int crow = l * 4;
  const int ccol = frow;
#pragma unroll
  for (int m = 0; m < 4; ++m) {
#pragma unroll
    for (int rr = 0; rr < 4; ++rr) {
      const int rowl = wr + m * 16 + crow + rr;
      const long row = (long)bi * 256 + rowl;
      const float rsv = RSDIV ? (1.0f / rs[(long)bz * SEQL + row]) : 1.0f;
#pragma unroll
      for (int n = 0; n < 4; ++n) {
        const int coll = wc + n * 16 + ccol;
        const int colg = bj * 128 + coll;
        float v = acc[m][n][rr];
        if (RSDIV) v *= rsv;
        if (BIAS)  v += bias[colg];
        if (QKVSC) v *= (colg < HID ? 0.03125f : 1.0f);
        C[(long)bz * sC + row * N + colg] = (OutT)v;
      }
    }
  }
}

// ---------------- scores + W2, one dispatch, grid (17,8,4), XCD-chunked ----------------
// Chunked XCD swizzle: lg = (lin%8)*68 + lin/8 -> each XCD owns a contiguous 68-block
// range = one 4-bi half-batch (4 Q panels + <=16 K panels + its Wo/V share) so panel
// re-fetch stays inside one L2 (R13: FETCH 133MB, HBM-bound; predict ~60MB).
// Live blocks (bj <= 2bi+1): P' tile = exp(q.k^T) causal (max-free), bf16, + atomic
// row sums into rs. Dead blocks (256 = exactly W2's tiles): W2 = Wo @ V^T — replaces
// both the V->VT transpose and the output projection (out = (P' W2^T)/rs + bo).
__global__ __launch_bounds__(512, 4)
void scores_w2(const bf16* __restrict__ Q, const bf16* __restrict__ Kp,
               const bf16* __restrict__ Wo, const bf16* __restrict__ V,
               bf16* __restrict__ P, bf16* __restrict__ W2, float* __restrict__ rs) {
  const int lin = blockIdx.x + 17 * blockIdx.y + 136 * blockIdx.z;  // grid (17,8,4)
  const int lg = (lin & 7) * 68 + (lin >> 3);
  const int bz = lg / 136;
  const int rem = lg % 136;
  const int bi = rem / 17, bj = rem % 17;
  const int t = threadIdx.x;
  const bool live = (bj <= 2 * bi + 1);
  const bf16 *Ab, *Bb;
  bf16* Cb;
  int lda, ldb;
  if (live) {
    Ab = Q + ((long)bz * SEQL + (long)bi * 256) * (3 * HID);
    Bb = Kp + ((long)bz * SEQL + (long)bj * 128) * (3 * HID);
    Cb = P + ((long)bz * SEQL + (long)bi * 256) * SEQL + bj * 128;
    lda = 3 * HID; ldb = 3 * HID;
  } else {
    // dense rank over dead slots: per-bi dead = 15-2bi, prefix = 15bi - bi(bi-1)
    const int rank = bz * 64 + (15 * bi - bi * (bi - 1)) + (bj - (2 * bi + 2));  // 0..255
    const int wz = rank >> 6, r = rank & 63, mi = r >> 4, nj = r & 15;
    Ab = Wo + (long)mi * 256 * HID;
    Bb = V + ((long)wz * SEQL + (long)nj * 128) * (3 * HID);
    Cb = W2 + ((long)wz * HID + (long)mi * 256) * SEQL + nj * 128;
    lda = HID; ldb = 3 * HID;
  }
  const int nt = 32;  // K = 1024

  __shared__ bf16 lds[3][12288];
  PIPE_DECLS
  PIPE_LOOP

  const int crow = l * 4;
  const int ccol = frow;
#pragma unroll
  for (int m = 0; m < 4; ++m) {
#pragma unroll
    for (int rr = 0; rr < 4; ++rr) {
      const int rowl = wr + m * 16 + crow + rr;
      float part = 0.0f;
#pragma unroll
      for (int n = 0; n < 4; ++n) {
        const int coll = wc + n * 16 + ccol;
        float v = acc[m][n][rr];
        if (live) {
          const int row = bi * 256 + rowl;
          const int col = bj * 128 + coll;
          v = (col <= row) ? __expf(v) : 0.0f;  // causal mask + max-free exp
          part += v;
        }
        Cb[(long)rowl * SEQL + coll] = (bf16)v;
      }
      if (live) {
        part += __shfl_xor(part, 1);
        part += __shfl_xor(part, 2);
        part += __shfl_xor(part, 4);
        part += __shfl_xor(part, 8);
        if (frow == 0) atomicAdd(&rs[(long)bz * SEQL + bi * 256 + rowl], part);
      }
    }
  }
}

extern "C" void kernel_launch(void* const* d_in, const int* in_sizes, int n_in,
                              void* d_out, int out_size, void* d_ws, size_t ws_size,
                              hipStream_t stream) {
  const float* x  = (const float*)d_in[0];
  const float* Wq = (const float*)d_in[1];
  const float* bq = (const float*)d_in[2];
  const float* Wk = (const float*)d_in[3];
  const float* bk = (const float*)d_in[4];
  const float* Wv = (const float*)d_in[5];
  const float* bv = (const float*)d_in[6];
  const float* Wo = (const float*)d_in[7];
  const float* bo = (const float*)d_in[8];
  float* out = (float*)d_out;

  // workspace (~136.4 MiB), lifetime-safe aliasing (as R13):
  char* ws = (char*)d_ws;
  bf16*  XB    = (bf16*)(ws);
  bf16*  WQKVB = (bf16*)(ws + 16777216L);
  float* bqkv  = (float*)(ws + 23068672L);
  bf16*  QKV   = (bf16*)(ws + 33554432L);
  bf16*  W2    = (bf16*)(ws + 83886080L);
  bf16*  WOB   = (bf16*)(ws + 100663296L);
  bf16*  P     = (bf16*)(ws + 102760448L);
  float* RS    = (float*)(ws + 136314880L);

  // 1) fused casts + bias concat + RS zero
  cast_all<<<12332, 256, 0, stream>>>(x, Wq, Wk, Wv, Wo, bq, bk, bv, XB, WQKVB, WOB, bqkv, RS);

  // 2) QKV projection: [8192,1024] x [3072,1024]^T; q-cols scaled 1/32 (XCD-swizzled)
  gemm_nt<bf16, true, false, false, true, true><<<dim3(24, 32, 1), 512, 0, stream>>>(
      XB, WQKVB, bqkv, QKV, nullptr, HID, HID, HID, 3 * HID, 0, 0, 0);

  // 3) P' = exp(q.k^T) causal + atomic row sums; dead causal slots compute W2 = Wo V^T
  scores_w2<<<dim3(17, 8, NB), 512, 0, stream>>>(
      QKV, QKV + HID, WOB, QKV + 2 * HID, P, W2, RS);

  // 4) out = (P' @ W2^T) / rowsum + bo   (causal K-limit, 256-granular)
  gemm_nt<float, true, true, true, false, false><<<dim3(8, 8, NB), 512, 0, stream>>>(
      P, W2, bo, out, RS, SEQL, SEQL, SEQL, HID,
      (long)SEQL * SEQL, (long)HID * SEQL, (long)SEQL * HID);
}